// Round 5
// baseline (220.485 us; speedup 1.0000x reference)
//
#include <hip/hip_runtime.h>

#define NORD 24
#define LL 32
#define MMLEN 3073

// 1/j! for j=0..25
static constexpr float INVF[26] = {
    1.0f, 1.0f, 5.0e-1f, 1.66666672e-1f, 4.16666679e-2f, 8.33333377e-3f,
    1.38888892e-3f, 1.98412701e-4f, 2.48015876e-5f, 2.75573195e-6f,
    2.75573188e-7f, 2.50521089e-8f, 2.08767563e-9f, 1.60590438e-10f,
    1.14707458e-11f, 7.64716373e-13f, 4.77947733e-14f, 2.81145725e-15f,
    1.56192069e-16f, 8.22063525e-18f, 4.11031762e-19f, 1.95729410e-20f,
    8.89679139e-22f, 3.86817017e-23f, 1.61173757e-24f, 6.44695028e-26f};

// trapezoidal pulse, f32 arithmetic replicating the jnp reference
__device__ __forceinline__ float pulsef(float ts) {
    const float rise = 5.0e-10f;
    const float w    = 9.999999999999999e-10f;
    const float e1   = 1.4999999999999998e-9f;
    const float e2   = 1.9999999999999997e-9f;
    const float fall = 5.0e-10f;
    if (ts < rise) return ts / rise;
    if (ts < e1)   return 1.0f;
    if (ts < e2)   return 1.0f - ((ts - w) - rise) / fall;
    return 0.0f;
}

// Full-wave DPP shifts (gfx9 lineage; VALU pipe, no LDS)
__device__ __forceinline__ float dpp_wshr1(float x) {   // lane l <- lane l-1; lane 0 <- 0
    return __int_as_float(__builtin_amdgcn_update_dpp(
        0, __float_as_int(x), 0x138, 0xF, 0xF, true));
}
__device__ __forceinline__ float dpp_wshl1(float x) {   // lane l <- lane l+1; lane 63 <- 0
    return __int_as_float(__builtin_amdgcn_update_dpp(
        0, __float_as_int(x), 0x130, 0xF, 0xF, true));
}
template <int CTRL>
__device__ __forceinline__ float dpp_movf(float x) {
    return __int_as_float(__builtin_amdgcn_update_dpp(
        0, __float_as_int(x), CTRL, 0xF, 0xF, true));
}

// One term of the power recursion: t <- (M*dt) * t, midv <- new mid component.
// Layout: lane l = chain position l; register b = branch b.
// midv is only meaningful in lane 0 (sole consumer); other lanes carry garbage.
__device__ __forceinline__ void term_step(float (&t)[16], float& midv,
                                          const float (&al)[16],
                                          const float (&be)[16],
                                          const float (&cM)[16],
                                          bool lane0) {
    // mid_new = sum_b cM[b]*t_b[pos 0]: per-lane register reduction,
    // true value lands in lane 0. Two chains to shorten latency.
    float h0 = cM[0] * t[0];
    float h1 = cM[1] * t[1];
#pragma unroll
    for (int b = 2; b < 16; b += 2) {
        h0 = fmaf(cM[b],     t[b],     h0);
        h1 = fmaf(cM[b + 1], t[b + 1], h1);
    }
    float hv = h0 + h1;

    float nt[16];
#pragma unroll
    for (int b = 0; b < 16; ++b) {
        float tl = dpp_wshr1(t[b]);       // left neighbor (pos l-1)
        tl = lane0 ? midv : tl;           // pos 0 couples to v_mid
        float tr = dpp_wshl1(t[b]);       // right neighbor (pos l+1); lane63 -> 0 (be=0)
        nt[b] = fmaf(al[b], tl, be[b] * tr);
    }
    midv = hv;
#pragma unroll
    for (int b = 0; b < 16; ++b) t[b] = nt[b];
}

// x <- (sum_{j<=NORD} (M dt)^j / j!) x ; xm is the mid component (lane 0)
__device__ __forceinline__ void eapply(float (&x)[16], float& xm,
                                       const float (&al)[16],
                                       const float (&be)[16],
                                       const float (&cM)[16],
                                       bool lane0) {
    float t[16], acc[16];
#pragma unroll
    for (int b = 0; b < 16; ++b) { t[b] = x[b]; acc[b] = x[b]; }
    float midv = xm, accm = xm;
#pragma unroll
    for (int j = 1; j <= NORD; ++j) {
        term_step(t, midv, al, be, cM, lane0);
        const float f = INVF[j];
#pragma unroll
        for (int b = 0; b < 16; ++b) acc[b] = fmaf(f, t[b], acc[b]);
        accm = fmaf(f, midv, accm);
    }
#pragma unroll
    for (int b = 0; b < 16; ++b) x[b] = acc[b];
    xm = accm;
}

// Meet-in-the-middle (round 4 math, lane-transposed layout):
// wave 0: forward chain (phib series, then z31 = E^31 phib)
// wave 1: backward chain w_a = (E^T)^a e_mid, a=0..32, folding u-weighted sums
// xm(T) = P0 . z0 + P31 . z31
__global__ __launch_bounds__(128) void sspuf_mitm(
    const int*   __restrict__ swp,
    const float* __restrict__ mismatch,
    const float* __restrict__ gm_c,
    const float* __restrict__ gm_l,
    const float* __restrict__ c_val,
    const float* __restrict__ l_val,
    const float* __restrict__ tp,
    float*       __restrict__ out)
{
    const int star = blockIdx.x;
    const int tid  = threadIdx.x;
    const int wave = tid >> 6;
    const int l    = tid & 63;          // chain position
    const int k    = l >> 1;            // LC section index
    const int par  = l & 1;             // 0 = current row (i[b,k]), 1 = voltage row (v[b,k])
    const bool lane0 = (l == 0);
    const float dt = tp[0] / 64.0f;

    const float* mm = mismatch + star * MMLEN;
    const float c_mid = 1e-9f * (mm[MMLEN - 1] * c_val[LL]);

    __shared__ float zbuf[2][1040];     // [0]=z0 (phib), [1]=z31; [.][1024] = mid

    float Pa[16], Pb[16];
    float Pam = 0.0f, Pbm = 0.0f;
#pragma unroll
    for (int b = 0; b < 16; ++b) { Pa[b] = 0.0f; Pb[b] = 0.0f; }

    float al[16], be[16], cM[16];

    if (wave == 0) {
        // ---------------- forward coefficients of (A*dt) ----------------
#pragma unroll
        for (int b = 0; b < 16; ++b) {
            const float* mb = mm + b * 192;
            const float swb = (float)swp[b];
            if (par == 0) {             // pos 2k = i[b,k]
                float Lm = 1e-9f * (mb[160 + k] * l_val[k]);
                float a  = dt * ((mb[64 + 2 * k] * gm_l[2 * k]) / Lm);
                if (k == 0) a *= swb;   // left neighbor is v_mid
                al[b] = a;
                be[b] = -dt * ((mb[64 + 2 * k + 1] * gm_l[2 * k + 1]) / Lm);
            } else {                    // pos 2k+1 = v[b,k]
                float C = 1e-9f * (mb[128 + k] * c_val[k]);
                al[b] = dt * ((mb[2 * k] * gm_c[2 * k]) / C);
                be[b] = (k < 31) ? (-dt * ((mb[2 * k + 1] * gm_c[2 * k + 1]) / C))
                                 : 0.0f;
            }
            cM[b] = -dt * (swb / c_mid);
        }

        // phib = dt * sum_{j>=0} t_j/(j+1)!,  t_0 = Bv (mid = 1/c_mid)
        float t[16], z[16];
#pragma unroll
        for (int b = 0; b < 16; ++b) { t[b] = 0.0f; z[b] = 0.0f; }
        float midv = 1.0f / c_mid;
        float zm = INVF[1] * midv;
#pragma unroll
        for (int j = 1; j <= NORD; ++j) {
            term_step(t, midv, al, be, cM, lane0);
            const float f = INVF[j + 1];
#pragma unroll
            for (int b = 0; b < 16; ++b) z[b] = fmaf(f, t[b], z[b]);
            zm = fmaf(f, midv, zm);
        }
#pragma unroll
        for (int b = 0; b < 16; ++b) z[b] *= dt;
        zm *= dt;

#pragma unroll
        for (int b = 0; b < 16; ++b) zbuf[0][b * 64 + l] = z[b];
        if (lane0) zbuf[0][1024] = zm;

        for (int s = 0; s < 31; ++s) eapply(z, zm, al, be, cM, lane0);

#pragma unroll
        for (int b = 0; b < 16; ++b) zbuf[1][b * 64 + l] = z[b];
        if (lane0) zbuf[1][1024] = zm;
    } else {
        // ---------------- backward coefficients of (A^T*dt) ----------------
        // alT[p] = dt*A[p-1][p] (p=0: mid coupling), beT[p] = dt*A[p+1][p]
#pragma unroll
        for (int b = 0; b < 16; ++b) {
            const float* mb = mm + b * 192;
            const float swb = (float)swp[b];
            if (par == 0) {             // pos 2k
                if (k == 0) {
                    al[b] = -dt * (swb / c_mid);
                } else {
                    float Cm1 = 1e-9f * (mb[128 + (k - 1)] * c_val[k - 1]);
                    al[b] = -dt * ((mb[2 * (k - 1) + 1] * gm_c[2 * (k - 1) + 1]) / Cm1);
                }
                float C = 1e-9f * (mb[128 + k] * c_val[k]);
                be[b] = dt * ((mb[2 * k] * gm_c[2 * k]) / C);
            } else {                    // pos 2k+1
                float Lm = 1e-9f * (mb[160 + k] * l_val[k]);
                al[b] = -dt * ((mb[64 + 2 * k + 1] * gm_l[2 * k + 1]) / Lm);
                if (k < 31) {
                    float Lp = 1e-9f * (mb[160 + (k + 1)] * l_val[k + 1]);
                    be[b] = dt * ((mb[64 + 2 * (k + 1)] * gm_l[2 * (k + 1)]) / Lp);
                } else {
                    be[b] = 0.0f;
                }
            }
            float Lm0 = 1e-9f * (mb[160] * l_val[0]);
            cM[b] = dt * ((swb * (mb[64] * gm_l[0])) / Lm0);
        }

        // w_0 = e_mid
        float w[16];
#pragma unroll
        for (int b = 0; b < 16; ++b) w[b] = 0.0f;
        float wm = 1.0f;

        for (int a = 0; a <= 32; ++a) {
            const float ua = (a <= 30) ? pulsef(((float)(63 - a) + 0.5f) * dt) : 0.0f;
            const float ub = pulsef(((float)(32 - a) + 0.5f) * dt);
#pragma unroll
            for (int b = 0; b < 16; ++b) {
                Pa[b] = fmaf(ua, w[b], Pa[b]);
                Pb[b] = fmaf(ub, w[b], Pb[b]);
            }
            Pam = fmaf(ua, wm, Pam);
            Pbm = fmaf(ub, wm, Pbm);
            if (a < 32) eapply(w, wm, al, be, cM, lane0);
        }
    }

    __syncthreads();

    if (wave == 1) {
        float part = 0.0f;
#pragma unroll
        for (int b = 0; b < 16; ++b)
            part += Pa[b] * zbuf[0][b * 64 + l] + Pb[b] * zbuf[1][b * 64 + l];
        if (lane0)
            part += Pam * zbuf[0][1024] + Pbm * zbuf[1][1024];
        // 64-lane sum
        part += dpp_movf<0xB1>(part);     // quad_perm xor1
        part += dpp_movf<0x4E>(part);     // quad_perm xor2
        part += dpp_movf<0x124>(part);    // row_ror:4
        part += dpp_movf<0x128>(part);    // row_ror:8
        part += __shfl_xor(part, 16);
        part += __shfl_xor(part, 32);
        if (lane0) atomicAdd(out, (star == 0) ? part : -part);
    }
}

extern "C" void kernel_launch(void* const* d_in, const int* in_sizes, int n_in,
                              void* d_out, int out_size, void* d_ws, size_t ws_size,
                              hipStream_t stream) {
    const int*   swp      = (const int*)d_in[0];
    const float* mismatch = (const float*)d_in[1];
    const float* gm_c     = (const float*)d_in[2];
    const float* gm_l     = (const float*)d_in[3];
    const float* c_val    = (const float*)d_in[4];
    const float* l_val    = (const float*)d_in[5];
    const float* tp       = (const float*)d_in[6];
    float* out = (float*)d_out;

    hipMemsetAsync(out, 0, sizeof(float), stream);
    sspuf_mitm<<<dim3(2), dim3(128), 0, stream>>>(
        swp, mismatch, gm_c, gm_l, c_val, l_val, tp, out);
}